// Round 11
// baseline (660.799 us; speedup 1.0000x reference)
//
#include <hip/hip_runtime.h>
#include <cstddef>
#include <cstdint>

typedef unsigned short u16;
typedef __attribute__((ext_vector_type(8))) short short8;   // 8 bf16 in 4 VGPRs
typedef __attribute__((ext_vector_type(4))) float floatx4;  // MFMA C/D

// scale (1/sqrt(2048)) * log2(e): folded into K at GEMM1 epilogue
#define C1_SCALE 0.031882111f
#define LOG2E    1.4426950408889634f

__device__ __forceinline__ u16 f2bf(float f) {
    union { float f; unsigned int i; } v; v.f = f;
    unsigned int b = v.i;
    b += 0x7FFFu + ((b >> 16) & 1u);   // RNE
    return (u16)(b >> 16);
}

__device__ __forceinline__ unsigned pk2bf(float lo, float hi) {
#if __has_builtin(__builtin_amdgcn_cvt_pk_bf16_f32)
    auto v = __builtin_amdgcn_cvt_pk_bf16_f32(lo, hi);
    union { decltype(v) b; unsigned u; } c; c.b = v; return c.u;
#else
    return (unsigned)f2bf(lo) | ((unsigned)f2bf(hi) << 16);
#endif
}
__device__ __forceinline__ int4 pack8bf(float4 a, float4 b) {
    union { unsigned u[4]; int4 v; } c;
    c.u[0] = pk2bf(a.x, a.y); c.u[1] = pk2bf(a.z, a.w);
    c.u[2] = pk2bf(b.x, b.y); c.u[3] = pk2bf(b.z, b.w);
    return c.v;
}
__device__ __forceinline__ float fastrcp(float x) {
#if __has_builtin(__builtin_amdgcn_rcpf)
    return __builtin_amdgcn_rcpf(x);
#else
    return 1.0f / x;
#endif
}
// swish via exp2 + rcp (no IEEE divide): ~1e-7 rel err, irrelevant at bf16
__device__ __forceinline__ float swishf(float s) {
    float e = __builtin_amdgcn_exp2f(-s * LOG2E);
    return s * fastrcp(1.0f + e);
}
__device__ __forceinline__ void glds16(const void* g, void* l) {
    __builtin_amdgcn_global_load_lds(
        (const __attribute__((address_space(1))) void*)g,
        (__attribute__((address_space(3))) void*)l, 16, 0, 0);
}

// ---------------------------------------------------------------------------
// Fused prep: cast x->bf16 (ids 0..4095), transpose W_fc (4096..7167),
// transpose W_fc2 (7168..8191).
// ---------------------------------------------------------------------------
__global__ __launch_bounds__(256) void prep_kernel(
    const float* __restrict__ x,     u16* __restrict__ xb,
    const float* __restrict__ W_fc,  u16* __restrict__ WfcT,
    const float* __restrict__ W_fc2, u16* __restrict__ Wfc2T)
{
    const int id = blockIdx.x;
    if (id < 4096) {
        const size_t i = ((size_t)id * 256 + threadIdx.x) * 8;
        float4 a = *(const float4*)&x[i];
        float4 b = *(const float4*)&x[i + 4];
        *(int4*)&xb[i] = pack8bf(a, b);
        return;
    }
    __shared__ u16 t[32][33];
    const float* src; u16* dst; int R, C, bx, by;
    if (id < 7168) {
        const int w = id - 4096;                 // 96 x 32 tiles
        bx = w % 96; by = w / 96; src = W_fc; dst = WfcT; R = 1024; C = 3072;
    } else {
        const int w = id - 7168;                 // 32 x 32 tiles
        bx = w % 32; by = w / 32; src = W_fc2; dst = Wfc2T; R = 1024; C = 1024;
    }
    const int tx = threadIdx.x & 31, ty = threadIdx.x >> 5;
    const int r0 = by * 32, c0 = bx * 32;
#pragma unroll
    for (int i = 0; i < 4; ++i)
        t[ty + i * 8][tx] = f2bf(src[(size_t)(r0 + ty + i * 8) * C + c0 + tx]);
    __syncthreads();
#pragma unroll
    for (int i = 0; i < 4; ++i)
        dst[(size_t)(c0 + ty + i * 8) * R + r0 + tx] = t[tx][ty + i * 8];
}

// ---------------------------------------------------------------------------
// m97-style GEMM core: 128x128 tile, BK=64, global_load_lds(16B) staging into
// UNPADDED As/Bs[128][64] with XOR swizzle in the SOURCE address.
// ---------------------------------------------------------------------------
#define GEMM_STAGE(AP, BP, Kdim)                                              \
    {                                                                          \
        _Pragma("unroll")                                                      \
        for (int i = 0; i < 4; ++i) {                                          \
            const int row = i * 32 + (tid >> 3);                               \
            const int gp  = (tid & 7) ^ (row & 7);                             \
            glds16(&AP[(size_t)(row0 + row) * Kdim + k0 + gp * 8],             \
                   &As[i * 32 + wid * 8][0]);                                  \
            glds16(&BP[(size_t)(col0 + row) * Kdim + k0 + gp * 8],             \
                   &Bs[i * 32 + wid * 8][0]);                                  \
        }                                                                      \
    }

#define GEMM_COMPUTE()                                                         \
    {                                                                          \
        _Pragma("unroll")                                                      \
        for (int kc = 0; kc < 2; ++kc) {                                       \
            short8 af[4], bf[4];                                               \
            const int gl = ((kc * 4 + quad) ^ (l16 & 7)) * 8;                  \
            _Pragma("unroll")                                                  \
            for (int mt = 0; mt < 4; ++mt)                                     \
                af[mt] = *(const short8*)&As[wm * 64 + mt * 16 + l16][gl];     \
            _Pragma("unroll")                                                  \
            for (int nt = 0; nt < 4; ++nt)                                     \
                bf[nt] = *(const short8*)&Bs[wn * 64 + nt * 16 + l16][gl];     \
            _Pragma("unroll")                                                  \
            for (int mt = 0; mt < 4; ++mt)                                     \
                _Pragma("unroll")                                              \
                for (int nt = 0; nt < 4; ++nt)                                 \
                    acc[mt][nt] = __builtin_amdgcn_mfma_f32_16x16x32_bf16(     \
                        af[mt], bf[nt], acc[mt][nt], 0, 0, 0);                 \
        }                                                                      \
    }

// ---------------------------------------------------------------------------
// GEMM1 (QKV projection): s = xb(bf16) @ WfcT^T + b_fc; sw = swish(s).
// Every 64-col half of a 128-col tile is purely q, k, or v:
//   col0%384==0  : [q(h) | k(h)]   col0%384==128: [v(h) | q(h+1)]
//   col0%384==256: [k(h) | v(h)]
// q/k direct to qk[row][h*128+w] (k pre-scaled by C1); v transposed through
// LDS (reusing As/Bs) and written as coalesced 64B/lane vT rows.
// ---------------------------------------------------------------------------
__global__ __launch_bounds__(256) void gemm_qkv_kernel(
    const u16* __restrict__ A, const u16* __restrict__ BT,
    const float* __restrict__ bias, u16* __restrict__ qk, u16* __restrict__ vT)
{
    const int K = 1024;
    const int tid  = threadIdx.x;
    const int wid  = tid >> 6;
    const int lane = tid & 63;
    const int quad = lane >> 4;
    const int l16  = lane & 15;
    const int wm = wid >> 1, wn = wid & 1;
    const int row0 = blockIdx.y * 128, col0 = blockIdx.x * 128;

    __shared__ __align__(16) u16 SMEM[2][128][64];
    auto& As = SMEM[0];
    auto& Bs = SMEM[1];
    u16 (*Vs)[136] = (u16(*)[136])&SMEM[0][0][0];  // 64x136 = 17408 B, fits

    floatx4 acc[4][4] = {};

    for (int k0 = 0; k0 < K; k0 += 64) {
        if (k0) __syncthreads();
        GEMM_STAGE(A, BT, K);
        __syncthreads();
        GEMM_COMPUTE();
    }

    float bb[4];
#pragma unroll
    for (int nt = 0; nt < 4; ++nt)
        bb[nt] = bias[col0 + wn * 64 + nt * 16 + l16];

    const int m384  = col0 % 384;
    const bool hasv = (m384 != 0);
    const int  vwn  = (m384 == 128) ? 0 : 1;   // which half holds v
    const bool kscl = (m384 == 0 && wn == 1) || (m384 == 256 && wn == 0);
    const float scl = kscl ? C1_SCALE : 1.0f;
    const int b = row0 >> 11;

    if (hasv) __syncthreads();   // SMEM (As/Bs) reads done; reuse as Vs

#pragma unroll
    for (int mt = 0; mt < 4; ++mt) {
        const int rbase = row0 + wm * 64 + mt * 16 + quad * 4;
        const int rloc  = wm * 64 + mt * 16 + quad * 4;
#pragma unroll
        for (int nt = 0; nt < 4; ++nt) {
            float sw[4];
#pragma unroll
            for (int r = 0; r < 4; ++r)
                sw[r] = swishf(acc[mt][nt][r] + bb[nt]);
            if (hasv && wn == vwn) {
                union { u16 hh[4]; uint2 v; } pk;
#pragma unroll
                for (int r = 0; r < 4; ++r) pk.hh[r] = f2bf(sw[r]);
                *(uint2*)&Vs[nt * 16 + l16][rloc] = pk.v;
            } else {
                const int c = col0 + wn * 64 + nt * 16 + l16;
                const unsigned h = (unsigned)c / 192u;
                const int w = c - (int)h * 192;
#pragma unroll
                for (int r = 0; r < 4; ++r)
                    qk[(size_t)(rbase + r) * 2048 + h * 128 + w] = f2bf(sw[r] * scl);
            }
        }
    }

    if (hasv) {
        __syncthreads();
        const int hv = (m384 == 128) ? (col0 / 192) : ((col0 + 64) / 192);
        const int d  = tid >> 2;            // 0..63
        const int ch = (tid & 3) * 32;      // 0..96
        const int l0b = row0 & 2047;
        u16* dst = &vT[((size_t)(b * 16 + hv) * 64 + d) * 2048 + l0b + ch];
#pragma unroll
        for (int q = 0; q < 4; ++q)
            *(int4*)&dst[q * 8] = *(const int4*)&Vs[d][ch + q * 8];
    }
}

// ---------------------------------------------------------------------------
// GEMM2: y(fp32) = x + swish(newv(bf16) @ Wfc2T^T + b_fc2)
// ---------------------------------------------------------------------------
__global__ __launch_bounds__(256) void gemm_out_kernel(
    const u16* __restrict__ A, const u16* __restrict__ BT,
    const float* __restrict__ bias, const float* __restrict__ xres,
    float* __restrict__ out)
{
    const int K = 1024, N = 1024;
    const int tid  = threadIdx.x;
    const int wid  = tid >> 6;
    const int lane = tid & 63;
    const int quad = lane >> 4;
    const int l16  = lane & 15;
    const int wm = wid >> 1, wn = wid & 1;
    const int row0 = blockIdx.y * 128, col0 = blockIdx.x * 128;

    __shared__ __align__(16) u16 As[128][64];
    __shared__ __align__(16) u16 Bs[128][64];

    floatx4 acc[4][4] = {};

    for (int k0 = 0; k0 < K; k0 += 64) {
        if (k0) __syncthreads();
        GEMM_STAGE(A, BT, K);
        __syncthreads();
        GEMM_COMPUTE();
    }

    float bb[4];
#pragma unroll
    for (int nt = 0; nt < 4; ++nt)
        bb[nt] = bias[col0 + wn * 64 + nt * 16 + l16];

#pragma unroll
    for (int mt = 0; mt < 4; ++mt) {
#pragma unroll
        for (int nt = 0; nt < 4; ++nt) {
#pragma unroll
            for (int r = 0; r < 4; ++r) {
                int row = row0 + wm * 64 + mt * 16 + quad * 4 + r;
                int col = col0 + wn * 64 + nt * 16 + l16;
                float sw = swishf(acc[mt][nt][r] + bb[nt]);
                out[(size_t)row * N + col] = xres[(size_t)row * N + col] + sw;
            }
        }
    }
}

// ---------------------------------------------------------------------------
// Flash attention, S^T orientation, no-max softmax, XCD-swizzled 1D grid.
// SPLIT-K IN BLOCK: 512 threads, 8 waves. Waves 0-3 (half=0) process keys
// 0..1023, waves 4-7 keys 1024..2047; all cover the same 256 q-rows with
// 4 i-tiles/wave (r10's DS-reads-per-element) at DOUBLE the waves/SIMD
// (r10 plateau = thin latency hiding at 2 waves/SIMD). No-max softmax makes
// the combine additive: O=Oa+Ob, l=la+lb via a small LDS epilogue.
// LDS: KV[2][2][64][64] 32K + Ps[8][16][64] 16K = 48K -> 2 blocks/CU,
// 16 waves/CU. Epilogue combine buffer aliases the dead KV region.
// ---------------------------------------------------------------------------
__global__ __launch_bounds__(512, 4) void attn_kernel(
    const u16* __restrict__ qk, const u16* __restrict__ vT,
    u16* __restrict__ newv)
{
    const int tid  = threadIdx.x;
    const int wid  = tid >> 6;        // 0..7
    const int half = tid >> 8;        // 0,1: key half
    const int w4   = wid & 3;         // q sub-tile group
    const int lane = tid & 63;
    const int quad = lane >> 4;
    const int l16  = lane & 15;
    const int id = blockIdx.x;
    const int qt = id >> 6;           // 0..7 (256 q-rows each)
    const int hb = id & 63;           // id%8 = hb%8 -> same XCD per (b,h)
    const int h  = hb & 15;
    const int b  = hb >> 4;

    const u16* qkb = qk + (size_t)b * 2048 * 2048;          // [l][h*128+w]
    const u16* vTb = vT + (size_t)(b * 16 + h) * 64 * 2048; // [d][l]

    short8 qf[4][2];
#pragma unroll
    for (int it = 0; it < 4; ++it) {
        const int qrow = qt * 256 + w4 * 64 + it * 16 + l16;
        const u16* qp = &qkb[(size_t)qrow * 2048 + h * 128];
        qf[it][0] = *(const short8*)&qp[quad * 8];
        qf[it][1] = *(const short8*)&qp[32 + quad * 8];
    }

    const short one = (short)0x3F80;  // bf16 1.0
    const short8 ones = {one, one, one, one, one, one, one, one};

    __shared__ __align__(16) u16 KV[2][2][64][64];  // [half][K=0/V=1][row][col]
    __shared__ __align__(16) u16 Ps[8][16][64];     // per-wave (i, j) swizzled

    // staging within half: t256 = tid&255 covers the half's 64x64 K + V tiles
    const int t256 = tid & 255;
    const int srow = t256 >> 3;
    const int sg0  = (t256 & 7) ^ (srow & 7);
    const int kbase = half * 1024;

    floatx4 oacc[4][4] = {};
    floatx4 sumacc[4] = {};

    for (int kt = 0; kt < 16; ++kt) {
        const int k0 = kbase + kt * 64;
        if (kt) __syncthreads();   // guard LDS reuse
#pragma unroll
        for (int i = 0; i < 2; ++i) {
            const int row = i * 32 + srow;
            glds16(&qkb[(size_t)(k0 + row) * 2048 + h * 128 + 64 + sg0 * 8],
                   &KV[half][0][i * 32 + w4 * 8][0]);
            glds16(&vTb[(size_t)row * 2048 + k0 + sg0 * 8],
                   &KV[half][1][i * 32 + w4 * 8][0]);
        }
        __syncthreads();           // vmcnt drained -> tiles visible

        // K/V fragments once into registers, reused across 4 i-tiles.
        short8 kf[2][4], vf[2][4];
#pragma unroll
        for (int kc = 0; kc < 2; ++kc) {
            const int gl = ((kc * 4 + quad) ^ (l16 & 7)) * 8;
#pragma unroll
            for (int nt = 0; nt < 4; ++nt) {
                kf[kc][nt] = *(const short8*)&KV[half][0][nt * 16 + l16][gl];
                vf[kc][nt] = *(const short8*)&KV[half][1][nt * 16 + l16][gl];
            }
        }

#pragma unroll
        for (int it = 0; it < 4; ++it) {
            // S^T: sacc[nt][r] = (K*C1)[j=nt*16+quad*4+r] . Q[i=l16]
            floatx4 sacc[4] = {};
#pragma unroll
            for (int kc = 0; kc < 2; ++kc)
#pragma unroll
                for (int nt = 0; nt < 4; ++nt)
                    sacc[nt] = __builtin_amdgcn_mfma_f32_16x16x32_bf16(
                        kf[kc][nt], qf[it][kc], sacc[nt], 0, 0, 0);

            // p = exp2(s) -> swizzled Ps (wave-private, in-order DS pipe)
#pragma unroll
            for (int nt = 0; nt < 4; ++nt) {
                float p0 = __builtin_amdgcn_exp2f(sacc[nt][0]);
                float p1 = __builtin_amdgcn_exp2f(sacc[nt][1]);
                float p2 = __builtin_amdgcn_exp2f(sacc[nt][2]);
                float p3 = __builtin_amdgcn_exp2f(sacc[nt][3]);
                union { unsigned u[2]; uint2 v; } pk;
                pk.u[0] = pk2bf(p0, p1);
                pk.u[1] = pk2bf(p2, p3);
                const int col = (((nt * 2 + (quad >> 1)) ^ (l16 & 7)) * 8) + (quad & 1) * 4;
                *(uint2*)&Ps[wid][l16][col] = pk.v;
            }
            // O^T += V^T . P^T ; row-sums += ones . P^T
#pragma unroll
            for (int kc = 0; kc < 2; ++kc) {
                const int gl = ((kc * 4 + quad) ^ (l16 & 7)) * 8;
                short8 pf = *(const short8*)&Ps[wid][l16][gl];
                sumacc[it] = __builtin_amdgcn_mfma_f32_16x16x32_bf16(ones, pf, sumacc[it], 0, 0, 0);
#pragma unroll
                for (int nt = 0; nt < 4; ++nt)
                    oacc[it][nt] = __builtin_amdgcn_mfma_f32_16x16x32_bf16(
                        vf[kc][nt], pf, oacc[it][nt], 0, 0, 0);
            }
        }
    }

    // Combine halves: half-1 writes partials to LDS (aliases dead KV region,
    // stride 20 floats = 16B-aligned, 2-way banks), half-0 adds + stores.
    float* combo = (float*)&KV[0][0][0][0];       // [4][64][20] floats
    float* combl = (float*)&Ps[0][0][0];          // [4][64] floats
#pragma unroll
    for (int it = 0; it < 4; ++it) {
        __syncthreads();
        if (half == 1) {
#pragma unroll
            for (int nt = 0; nt < 4; ++nt)
                *(floatx4*)&combo[(w4 * 64 + lane) * 20 + nt * 4] = oacc[it][nt];
            combl[w4 * 64 + lane] = sumacc[it][0];
        }
        __syncthreads();
        if (half == 0) {
            const float inv = fastrcp(sumacc[it][0] + combl[w4 * 64 + lane]);
            const int row = qt * 256 + w4 * 64 + it * 16 + l16;
            u16* orow = &newv[((size_t)b * 2048 + row) * 1024 + h * 64];
#pragma unroll
            for (int nt = 0; nt < 4; ++nt) {
                floatx4 ob = *(const floatx4*)&combo[(w4 * 64 + lane) * 20 + nt * 4];
                union { unsigned u[2]; uint2 v; } pk;
                pk.u[0] = pk2bf((oacc[it][nt][0] + ob[0]) * inv,
                                (oacc[it][nt][1] + ob[1]) * inv);
                pk.u[1] = pk2bf((oacc[it][nt][2] + ob[2]) * inv,
                                (oacc[it][nt][3] + ob[3]) * inv);
                *(uint2*)&orow[nt * 16 + quad * 4] = pk.v;
            }
        }
    }
}

// ---------------------------------------------------------------------------
// LayerNorm over D=1024 (no affine), fp32 in/out. One WAVE per row: no LDS,
// no barriers, pure shuffle reduction. Grid 2048 x 4 rows/block.
// ---------------------------------------------------------------------------
__global__ __launch_bounds__(256) void ln_kernel(
    const float* __restrict__ y, float* __restrict__ out)
{
    const int wid = threadIdx.x >> 6, lane = threadIdx.x & 63;
    const int row = blockIdx.x * 4 + wid;
    const float* yr = y + (size_t)row * 1024;
    float4 v[4];
    float s1 = 0.f, s2 = 0.f;
#pragma unroll
    for (int i = 0; i < 4; ++i) {
        v[i] = *(const float4*)&yr[lane * 4 + i * 256];
        s1 += v[i].x + v[i].y + v[i].z + v[i].w;
        s2 += v[i].x * v[i].x + v[i].y * v[i].y + v[i].z * v[i].z + v[i].w * v[i].w;
    }
#pragma unroll
    for (int off = 1; off < 64; off <<= 1) {
        s1 += __shfl_xor(s1, off, 64);
        s2 += __shfl_xor(s2, off, 64);
    }
    const float mu   = s1 * (1.0f / 1024.0f);
    const float var  = s2 * (1.0f / 1024.0f) - mu * mu;
    const float rstd = rsqrtf(var + 1e-5f);
    float* orow = out + (size_t)row * 1024;
#pragma unroll
    for (int i = 0; i < 4; ++i) {
        float4 o;
        o.x = (v[i].x - mu) * rstd; o.y = (v[i].y - mu) * rstd;
        o.z = (v[i].z - mu) * rstd; o.w = (v[i].w - mu) * rstd;
        *(float4*)&orow[lane * 4 + i * 256] = o;
    }
}

// ---------------------------------------------------------------------------
// FP32 I/O; bf16 internally.
// d_out (32 MiB) as scratch, fully overwritten by final LN:
//   [0,6M) WfcT | [6M,8M) Wfc2T | [8M,24M) xbf (then newv — xbf dead by attn)
// ws (48 MiB): [0,32M) qk (later aliased by y fp32) | [32M,48M) vT
// ---------------------------------------------------------------------------
extern "C" void kernel_launch(void* const* d_in, const int* in_sizes, int n_in,
                              void* d_out, int out_size, void* d_ws, size_t ws_size,
                              hipStream_t stream) {
    const float* x     = (const float*)d_in[0];
    const float* W_fc  = (const float*)d_in[1];
    const float* b_fc  = (const float*)d_in[2];
    const float* W_fc2 = (const float*)d_in[3];
    const float* b_fc2 = (const float*)d_in[4];
    float* out = (float*)d_out;

    char* ob = (char*)d_out;
    u16* WfcT  = (u16*)ob;
    u16* Wfc2T = (u16*)(ob + 6291456);
    u16* xbf   = (u16*)(ob + 8388608);   // [8192,1024] bf16
    u16* newv  = (u16*)(ob + 8388608);   // reuses xbf region after attn

    char* ws = (char*)d_ws;
    u16*   qk = (u16*)ws;                // [8192, H*128]
    u16*   vT = (u16*)(ws + 33554432);   // [B*H*64, 2048]
    float* y  = (float*)ws;              // aliases qk (dead by GEMM2)

    prep_kernel<<<dim3(8192), 256, 0, stream>>>(x, xbf, W_fc, WfcT, W_fc2, Wfc2T);

    gemm_qkv_kernel<<<dim3(24, 64), 256, 0, stream>>>(xbf, WfcT, b_fc, qk, vT);

    attn_kernel<<<dim3(512), 512, 0, stream>>>(qk, vT, newv);

    gemm_out_kernel<<<dim3(8, 64), 256, 0, stream>>>(newv, Wfc2T, b_fc2, x, y);

    ln_kernel<<<dim3(2048), 256, 0, stream>>>(y, out);
}

// Round 12
// 282.565 us; speedup vs baseline: 2.3386x; 2.3386x over previous
//
#include <hip/hip_runtime.h>
#include <cstddef>
#include <cstdint>

typedef unsigned short u16;
typedef __attribute__((ext_vector_type(8))) short short8;   // 8 bf16 in 4 VGPRs
typedef __attribute__((ext_vector_type(4))) float floatx4;  // MFMA C/D

// scale (1/sqrt(2048)) * log2(e): folded into K at GEMM1 epilogue
#define C1_SCALE 0.031882111f
#define LOG2E    1.4426950408889634f

__device__ __forceinline__ u16 f2bf(float f) {
    union { float f; unsigned int i; } v; v.f = f;
    unsigned int b = v.i;
    b += 0x7FFFu + ((b >> 16) & 1u);   // RNE
    return (u16)(b >> 16);
}

__device__ __forceinline__ unsigned pk2bf(float lo, float hi) {
#if __has_builtin(__builtin_amdgcn_cvt_pk_bf16_f32)
    auto v = __builtin_amdgcn_cvt_pk_bf16_f32(lo, hi);
    union { decltype(v) b; unsigned u; } c; c.b = v; return c.u;
#else
    return (unsigned)f2bf(lo) | ((unsigned)f2bf(hi) << 16);
#endif
}
__device__ __forceinline__ int4 pack8bf(float4 a, float4 b) {
    union { unsigned u[4]; int4 v; } c;
    c.u[0] = pk2bf(a.x, a.y); c.u[1] = pk2bf(a.z, a.w);
    c.u[2] = pk2bf(b.x, b.y); c.u[3] = pk2bf(b.z, b.w);
    return c.v;
}
__device__ __forceinline__ float fastrcp(float x) {
#if __has_builtin(__builtin_amdgcn_rcpf)
    return __builtin_amdgcn_rcpf(x);
#else
    return 1.0f / x;
#endif
}
// swish via exp2 + rcp (no IEEE divide): ~1e-7 rel err, irrelevant at bf16
__device__ __forceinline__ float swishf(float s) {
    float e = __builtin_amdgcn_exp2f(-s * LOG2E);
    return s * fastrcp(1.0f + e);
}
__device__ __forceinline__ void glds16(const void* g, void* l) {
    __builtin_amdgcn_global_load_lds(
        (const __attribute__((address_space(1))) void*)g,
        (__attribute__((address_space(3))) void*)l, 16, 0, 0);
}

// ---------------------------------------------------------------------------
// Fused prep: cast x->bf16 (ids 0..4095), transpose W_fc (4096..7167),
// transpose W_fc2 (7168..8191).
// ---------------------------------------------------------------------------
__global__ __launch_bounds__(256) void prep_kernel(
    const float* __restrict__ x,     u16* __restrict__ xb,
    const float* __restrict__ W_fc,  u16* __restrict__ WfcT,
    const float* __restrict__ W_fc2, u16* __restrict__ Wfc2T)
{
    const int id = blockIdx.x;
    if (id < 4096) {
        const size_t i = ((size_t)id * 256 + threadIdx.x) * 8;
        float4 a = *(const float4*)&x[i];
        float4 b = *(const float4*)&x[i + 4];
        *(int4*)&xb[i] = pack8bf(a, b);
        return;
    }
    __shared__ u16 t[32][33];
    const float* src; u16* dst; int R, C, bx, by;
    if (id < 7168) {
        const int w = id - 4096;                 // 96 x 32 tiles
        bx = w % 96; by = w / 96; src = W_fc; dst = WfcT; R = 1024; C = 3072;
    } else {
        const int w = id - 7168;                 // 32 x 32 tiles
        bx = w % 32; by = w / 32; src = W_fc2; dst = Wfc2T; R = 1024; C = 1024;
    }
    const int tx = threadIdx.x & 31, ty = threadIdx.x >> 5;
    const int r0 = by * 32, c0 = bx * 32;
#pragma unroll
    for (int i = 0; i < 4; ++i)
        t[ty + i * 8][tx] = f2bf(src[(size_t)(r0 + ty + i * 8) * C + c0 + tx]);
    __syncthreads();
#pragma unroll
    for (int i = 0; i < 4; ++i)
        dst[(size_t)(c0 + ty + i * 8) * R + r0 + tx] = t[tx][ty + i * 8];
}

// ---------------------------------------------------------------------------
// m97-style GEMM core: 128x128 tile, BK=64, global_load_lds(16B) staging into
// UNPADDED As/Bs[128][64] with XOR swizzle in the SOURCE address.
// ---------------------------------------------------------------------------
#define GEMM_STAGE(AP, BP, Kdim)                                              \
    {                                                                          \
        _Pragma("unroll")                                                      \
        for (int i = 0; i < 4; ++i) {                                          \
            const int row = i * 32 + (tid >> 3);                               \
            const int gp  = (tid & 7) ^ (row & 7);                             \
            glds16(&AP[(size_t)(row0 + row) * Kdim + k0 + gp * 8],             \
                   &As[i * 32 + wid * 8][0]);                                  \
            glds16(&BP[(size_t)(col0 + row) * Kdim + k0 + gp * 8],             \
                   &Bs[i * 32 + wid * 8][0]);                                  \
        }                                                                      \
    }

#define GEMM_COMPUTE()                                                         \
    {                                                                          \
        _Pragma("unroll")                                                      \
        for (int kc = 0; kc < 2; ++kc) {                                       \
            short8 af[4], bf[4];                                               \
            const int gl = ((kc * 4 + quad) ^ (l16 & 7)) * 8;                  \
            _Pragma("unroll")                                                  \
            for (int mt = 0; mt < 4; ++mt)                                     \
                af[mt] = *(const short8*)&As[wm * 64 + mt * 16 + l16][gl];     \
            _Pragma("unroll")                                                  \
            for (int nt = 0; nt < 4; ++nt)                                     \
                bf[nt] = *(const short8*)&Bs[wn * 64 + nt * 16 + l16][gl];     \
            _Pragma("unroll")                                                  \
            for (int mt = 0; mt < 4; ++mt)                                     \
                _Pragma("unroll")                                              \
                for (int nt = 0; nt < 4; ++nt)                                 \
                    acc[mt][nt] = __builtin_amdgcn_mfma_f32_16x16x32_bf16(     \
                        af[mt], bf[nt], acc[mt][nt], 0, 0, 0);                 \
        }                                                                      \
    }

// ---------------------------------------------------------------------------
// GEMM1 (QKV projection): s = xb(bf16) @ WfcT^T + b_fc; sw = swish(s).
// Every 64-col half of a 128-col tile is purely q, k, or v:
//   col0%384==0  : [q(h) | k(h)]   col0%384==128: [v(h) | q(h+1)]
//   col0%384==256: [k(h) | v(h)]
// q/k direct to qk[row][h*128+w] (k pre-scaled by C1); v transposed through
// LDS (reusing As/Bs) and written as coalesced 64B/lane vT rows.
// ---------------------------------------------------------------------------
__global__ __launch_bounds__(256) void gemm_qkv_kernel(
    const u16* __restrict__ A, const u16* __restrict__ BT,
    const float* __restrict__ bias, u16* __restrict__ qk, u16* __restrict__ vT)
{
    const int K = 1024;
    const int tid  = threadIdx.x;
    const int wid  = tid >> 6;
    const int lane = tid & 63;
    const int quad = lane >> 4;
    const int l16  = lane & 15;
    const int wm = wid >> 1, wn = wid & 1;
    const int row0 = blockIdx.y * 128, col0 = blockIdx.x * 128;

    __shared__ __align__(16) u16 SMEM[2][128][64];
    auto& As = SMEM[0];
    auto& Bs = SMEM[1];
    u16 (*Vs)[136] = (u16(*)[136])&SMEM[0][0][0];  // 64x136 = 17408 B, fits

    floatx4 acc[4][4] = {};

    for (int k0 = 0; k0 < K; k0 += 64) {
        if (k0) __syncthreads();
        GEMM_STAGE(A, BT, K);
        __syncthreads();
        GEMM_COMPUTE();
    }

    float bb[4];
#pragma unroll
    for (int nt = 0; nt < 4; ++nt)
        bb[nt] = bias[col0 + wn * 64 + nt * 16 + l16];

    const int m384  = col0 % 384;
    const bool hasv = (m384 != 0);
    const int  vwn  = (m384 == 128) ? 0 : 1;   // which half holds v
    const bool kscl = (m384 == 0 && wn == 1) || (m384 == 256 && wn == 0);
    const float scl = kscl ? C1_SCALE : 1.0f;
    const int b = row0 >> 11;

    if (hasv) __syncthreads();   // SMEM (As/Bs) reads done; reuse as Vs

#pragma unroll
    for (int mt = 0; mt < 4; ++mt) {
        const int rbase = row0 + wm * 64 + mt * 16 + quad * 4;
        const int rloc  = wm * 64 + mt * 16 + quad * 4;
#pragma unroll
        for (int nt = 0; nt < 4; ++nt) {
            float sw[4];
#pragma unroll
            for (int r = 0; r < 4; ++r)
                sw[r] = swishf(acc[mt][nt][r] + bb[nt]);
            if (hasv && wn == vwn) {
                union { u16 hh[4]; uint2 v; } pk;
#pragma unroll
                for (int r = 0; r < 4; ++r) pk.hh[r] = f2bf(sw[r]);
                *(uint2*)&Vs[nt * 16 + l16][rloc] = pk.v;
            } else {
                const int c = col0 + wn * 64 + nt * 16 + l16;
                const unsigned h = (unsigned)c / 192u;
                const int w = c - (int)h * 192;
#pragma unroll
                for (int r = 0; r < 4; ++r)
                    qk[(size_t)(rbase + r) * 2048 + h * 128 + w] = f2bf(sw[r] * scl);
            }
        }
    }

    if (hasv) {
        __syncthreads();
        const int hv = (m384 == 128) ? (col0 / 192) : ((col0 + 64) / 192);
        const int d  = tid >> 2;            // 0..63
        const int ch = (tid & 3) * 32;      // 0..96
        const int l0b = row0 & 2047;
        u16* dst = &vT[((size_t)(b * 16 + hv) * 64 + d) * 2048 + l0b + ch];
#pragma unroll
        for (int q = 0; q < 4; ++q)
            *(int4*)&dst[q * 8] = *(const int4*)&Vs[d][ch + q * 8];
    }
}

// ---------------------------------------------------------------------------
// GEMM2: y(fp32) = x + swish(newv(bf16) @ Wfc2T^T + b_fc2)
// ---------------------------------------------------------------------------
__global__ __launch_bounds__(256) void gemm_out_kernel(
    const u16* __restrict__ A, const u16* __restrict__ BT,
    const float* __restrict__ bias, const float* __restrict__ xres,
    float* __restrict__ out)
{
    const int K = 1024, N = 1024;
    const int tid  = threadIdx.x;
    const int wid  = tid >> 6;
    const int lane = tid & 63;
    const int quad = lane >> 4;
    const int l16  = lane & 15;
    const int wm = wid >> 1, wn = wid & 1;
    const int row0 = blockIdx.y * 128, col0 = blockIdx.x * 128;

    __shared__ __align__(16) u16 As[128][64];
    __shared__ __align__(16) u16 Bs[128][64];

    floatx4 acc[4][4] = {};

    for (int k0 = 0; k0 < K; k0 += 64) {
        if (k0) __syncthreads();
        GEMM_STAGE(A, BT, K);
        __syncthreads();
        GEMM_COMPUTE();
    }

    float bb[4];
#pragma unroll
    for (int nt = 0; nt < 4; ++nt)
        bb[nt] = bias[col0 + wn * 64 + nt * 16 + l16];

#pragma unroll
    for (int mt = 0; mt < 4; ++mt) {
#pragma unroll
        for (int nt = 0; nt < 4; ++nt) {
#pragma unroll
            for (int r = 0; r < 4; ++r) {
                int row = row0 + wm * 64 + mt * 16 + quad * 4 + r;
                int col = col0 + wn * 64 + nt * 16 + l16;
                float sw = swishf(acc[mt][nt][r] + bb[nt]);
                out[(size_t)row * N + col] = xres[(size_t)row * N + col] + sw;
            }
        }
    }
}

// ---------------------------------------------------------------------------
// Flash attention, S^T orientation, no-max softmax, XCD-swizzled 1D grid.
// Round-10 structure (4 i-tiles/wave, 256 q-rows/block, grid 512, 256 thr)
// + K/V DOUBLE-BUFFER with ONE barrier/iter. Grid 512 = 2 blocks/CU by
// grid count, so the extra 16 KB LDS is free (r8's dbuf failed at 4-block
// occupancy; r10's 8 waves/CU leave staging latency exposed — here dbuf
// overlaps the DMA with the whole compute phase at zero occupancy cost).
// LDS = Ks 16K + Vt 16K + Ps 8K = 40960 B.
// ---------------------------------------------------------------------------
__global__ __launch_bounds__(256, 2) void attn_kernel(
    const u16* __restrict__ qk, const u16* __restrict__ vT,
    u16* __restrict__ newv)
{
    const int tid  = threadIdx.x;
    const int wid  = tid >> 6;
    const int lane = tid & 63;
    const int quad = lane >> 4;
    const int l16  = lane & 15;
    const int id = blockIdx.x;
    const int qt = id >> 6;          // 0..7 (256 q-rows each)
    const int hb = id & 63;          // id%8 = hb%8 -> same XCD per (b,h)
    const int h  = hb & 15;
    const int b  = hb >> 4;

    const u16* qkb = qk + (size_t)b * 2048 * 2048;          // [l][h*128+w]
    const u16* vTb = vT + (size_t)(b * 16 + h) * 64 * 2048; // [d][l]

    short8 qf[4][2];
#pragma unroll
    for (int it = 0; it < 4; ++it) {
        const int qrow = qt * 256 + wid * 64 + it * 16 + l16;
        const u16* qp = &qkb[(size_t)qrow * 2048 + h * 128];
        qf[it][0] = *(const short8*)&qp[quad * 8];
        qf[it][1] = *(const short8*)&qp[32 + quad * 8];
    }

    const short one = (short)0x3F80;  // bf16 1.0
    const short8 ones = {one, one, one, one, one, one, one, one};

    __shared__ __align__(16) u16 Ks[2][64][64];   // (buf, j, d) swizzled
    __shared__ __align__(16) u16 Vt[2][64][64];   // (buf, d, j) swizzled
    __shared__ __align__(16) u16 Ps[4][16][64];   // per-wave (i, j) swizzled

    // staging: row = i*32 + tid/8, 16B group (tid&7)^(row&7)
    const int srow = tid >> 3;
    const int sg0  = (tid & 7) ^ (srow & 7);

    floatx4 oacc[4][4] = {};
    floatx4 sumacc[4] = {};

    // prologue: stage tile 0 into buf 0
#pragma unroll
    for (int i = 0; i < 2; ++i) {
        const int row = i * 32 + srow;
        glds16(&qkb[(size_t)row * 2048 + h * 128 + 64 + sg0 * 8],
               &Ks[0][i * 32 + wid * 8][0]);
        glds16(&vTb[(size_t)row * 2048 + sg0 * 8],
               &Vt[0][i * 32 + wid * 8][0]);
    }

    for (int kt = 0; kt < 32; ++kt) {
        const int cur = kt & 1;
        __syncthreads();   // drains DMA for tile kt (and guards alt-buf reuse)

        if (kt + 1 < 32) {
            const int k0n = (kt + 1) * 64;
#pragma unroll
            for (int i = 0; i < 2; ++i) {
                const int row = i * 32 + srow;
                glds16(&qkb[(size_t)(k0n + row) * 2048 + h * 128 + 64 + sg0 * 8],
                       &Ks[cur ^ 1][i * 32 + wid * 8][0]);
                glds16(&vTb[(size_t)row * 2048 + k0n + sg0 * 8],
                       &Vt[cur ^ 1][i * 32 + wid * 8][0]);
            }
        }

        // K/V fragments once into registers, reused across 4 i-tiles.
        short8 kf[2][4], vf[2][4];
#pragma unroll
        for (int kc = 0; kc < 2; ++kc) {
            const int gl = ((kc * 4 + quad) ^ (l16 & 7)) * 8;
#pragma unroll
            for (int nt = 0; nt < 4; ++nt) {
                kf[kc][nt] = *(const short8*)&Ks[cur][nt * 16 + l16][gl];
                vf[kc][nt] = *(const short8*)&Vt[cur][nt * 16 + l16][gl];
            }
        }

#pragma unroll
        for (int it = 0; it < 4; ++it) {
            // S^T: sacc[nt][r] = (K*C1)[j=nt*16+quad*4+r] . Q[i=l16]
            floatx4 sacc[4] = {};
#pragma unroll
            for (int kc = 0; kc < 2; ++kc)
#pragma unroll
                for (int nt = 0; nt < 4; ++nt)
                    sacc[nt] = __builtin_amdgcn_mfma_f32_16x16x32_bf16(
                        kf[kc][nt], qf[it][kc], sacc[nt], 0, 0, 0);

            // p = exp2(s) -> swizzled Ps (wave-private, in-order DS pipe)
#pragma unroll
            for (int nt = 0; nt < 4; ++nt) {
                float p0 = __builtin_amdgcn_exp2f(sacc[nt][0]);
                float p1 = __builtin_amdgcn_exp2f(sacc[nt][1]);
                float p2 = __builtin_amdgcn_exp2f(sacc[nt][2]);
                float p3 = __builtin_amdgcn_exp2f(sacc[nt][3]);
                union { unsigned u[2]; uint2 v; } pk;
                pk.u[0] = pk2bf(p0, p1);
                pk.u[1] = pk2bf(p2, p3);
                const int col = (((nt * 2 + (quad >> 1)) ^ (l16 & 7)) * 8) + (quad & 1) * 4;
                *(uint2*)&Ps[wid][l16][col] = pk.v;
            }
            // O^T += V^T . P^T ; row-sums += ones . P^T
#pragma unroll
            for (int kc = 0; kc < 2; ++kc) {
                const int gl = ((kc * 4 + quad) ^ (l16 & 7)) * 8;
                short8 pf = *(const short8*)&Ps[wid][l16][gl];
                sumacc[it] = __builtin_amdgcn_mfma_f32_16x16x32_bf16(ones, pf, sumacc[it], 0, 0, 0);
#pragma unroll
                for (int nt = 0; nt < 4; ++nt)
                    oacc[it][nt] = __builtin_amdgcn_mfma_f32_16x16x32_bf16(
                        vf[kc][nt], pf, oacc[it][nt], 0, 0, 0);
            }
        }
    }

    // sumacc[it]: all regs hold sum_j P^T[j][i=l16] -> 1/l.
#pragma unroll
    for (int it = 0; it < 4; ++it) {
        const float inv = fastrcp(sumacc[it][0]);
        const int row = qt * 256 + wid * 64 + it * 16 + l16;
        u16* orow = &newv[((size_t)b * 2048 + row) * 1024 + h * 64];
#pragma unroll
        for (int nt = 0; nt < 4; ++nt) {
            union { unsigned u[2]; uint2 v; } pk;
            pk.u[0] = pk2bf(oacc[it][nt][0] * inv, oacc[it][nt][1] * inv);
            pk.u[1] = pk2bf(oacc[it][nt][2] * inv, oacc[it][nt][3] * inv);
            *(uint2*)&orow[nt * 16 + quad * 4] = pk.v;
        }
    }
}

// ---------------------------------------------------------------------------
// LayerNorm over D=1024 (no affine), fp32 in/out. One WAVE per row: no LDS,
// no barriers, pure shuffle reduction. Grid 2048 x 4 rows/block.
// ---------------------------------------------------------------------------
__global__ __launch_bounds__(256) void ln_kernel(
    const float* __restrict__ y, float* __restrict__ out)
{
    const int wid = threadIdx.x >> 6, lane = threadIdx.x & 63;
    const int row = blockIdx.x * 4 + wid;
    const float* yr = y + (size_t)row * 1024;
    float4 v[4];
    float s1 = 0.f, s2 = 0.f;
#pragma unroll
    for (int i = 0; i < 4; ++i) {
        v[i] = *(const float4*)&yr[lane * 4 + i * 256];
        s1 += v[i].x + v[i].y + v[i].z + v[i].w;
        s2 += v[i].x * v[i].x + v[i].y * v[i].y + v[i].z * v[i].z + v[i].w * v[i].w;
    }
#pragma unroll
    for (int off = 1; off < 64; off <<= 1) {
        s1 += __shfl_xor(s1, off, 64);
        s2 += __shfl_xor(s2, off, 64);
    }
    const float mu   = s1 * (1.0f / 1024.0f);
    const float var  = s2 * (1.0f / 1024.0f) - mu * mu;
    const float rstd = rsqrtf(var + 1e-5f);
    float* orow = out + (size_t)row * 1024;
#pragma unroll
    for (int i = 0; i < 4; ++i) {
        float4 o;
        o.x = (v[i].x - mu) * rstd; o.y = (v[i].y - mu) * rstd;
        o.z = (v[i].z - mu) * rstd; o.w = (v[i].w - mu) * rstd;
        *(float4*)&orow[lane * 4 + i * 256] = o;
    }
}

// ---------------------------------------------------------------------------
// FP32 I/O; bf16 internally.
// d_out (32 MiB) as scratch, fully overwritten by final LN:
//   [0,6M) WfcT | [6M,8M) Wfc2T | [8M,24M) xbf (then newv — xbf dead by attn)
// ws (48 MiB): [0,32M) qk (later aliased by y fp32) | [32M,48M) vT
// ---------------------------------------------------------------------------
extern "C" void kernel_launch(void* const* d_in, const int* in_sizes, int n_in,
                              void* d_out, int out_size, void* d_ws, size_t ws_size,
                              hipStream_t stream) {
    const float* x     = (const float*)d_in[0];
    const float* W_fc  = (const float*)d_in[1];
    const float* b_fc  = (const float*)d_in[2];
    const float* W_fc2 = (const float*)d_in[3];
    const float* b_fc2 = (const float*)d_in[4];
    float* out = (float*)d_out;

    char* ob = (char*)d_out;
    u16* WfcT  = (u16*)ob;
    u16* Wfc2T = (u16*)(ob + 6291456);
    u16* xbf   = (u16*)(ob + 8388608);   // [8192,1024] bf16
    u16* newv  = (u16*)(ob + 8388608);   // reuses xbf region after attn

    char* ws = (char*)d_ws;
    u16*   qk = (u16*)ws;                // [8192, H*128]
    u16*   vT = (u16*)(ws + 33554432);   // [B*H*64, 2048]
    float* y  = (float*)ws;              // aliases qk (dead by GEMM2)

    prep_kernel<<<dim3(8192), 256, 0, stream>>>(x, xbf, W_fc, WfcT, W_fc2, Wfc2T);

    gemm_qkv_kernel<<<dim3(24, 64), 256, 0, stream>>>(xbf, WfcT, b_fc, qk, vT);

    attn_kernel<<<dim3(512), 256, 0, stream>>>(qk, vT, newv);

    gemm_out_kernel<<<dim3(8, 64), 256, 0, stream>>>(newv, Wfc2T, b_fc2, x, y);

    ln_kernel<<<dim3(2048), 256, 0, stream>>>(y, out);
}